// Round 11
// baseline (256.665 us; speedup 1.0000x reference)
//
#include <hip/hip_runtime.h>
#include <stdint.h>
#include <math.h>

#define BB 32
#define TT 2048
#define CC 768
#define NTOK (BB*TT)                     // 65536
#define NTOT 50331648LL                  // BB*TT*CC
#define RANK0 25165823LL                 // NTOT/2 - 1
#define RANK1 25165824LL                 // NTOT/2
#define CTH 0.0009765625f                // 2^-10
#define NBLK 2048
#define CSTRIDE 64                       // compact slots per block
#define KCAP 4096                        // per-bucket LDS gather capacity

typedef float nf4 __attribute__((ext_vector_type(4)));   // native vec for nontemporal

// ---- monotone float<->uint mapping (order-preserving) ----
__device__ inline unsigned int f2key(float f) {
    unsigned int u = __float_as_uint(f);
    return (u & 0x80000000u) ? ~u : (u | 0x80000000u);
}
__device__ inline float key2f(unsigned int k) {
    unsigned int u = (k & 0x80000000u) ? (k ^ 0x80000000u) : ~k;
    return __uint_as_float(u);
}

// ---- 1024-thread bucket select: NB bins, rank k -> res[0]=bin res[1]=prefix ----
template<int NB>
__device__ void sel1024(const unsigned int* __restrict__ hist,
                        unsigned long long k, unsigned int* res,
                        unsigned long long* pscan)
{
    const int t = threadIdx.x;
    constexpr int PER = NB / 1024;
    unsigned int loc[PER];
    unsigned long long lsum = 0;
    #pragma unroll
    for (int i = 0; i < PER; ++i) { loc[i] = hist[t * PER + i]; lsum += loc[i]; }
    pscan[t] = lsum;
    __syncthreads();
    for (int off = 1; off < 1024; off <<= 1) {
        unsigned long long v = (t >= off) ? pscan[t - off] : 0ULL;
        __syncthreads();
        pscan[t] += v;
        __syncthreads();
    }
    unsigned long long excl = (t == 0) ? 0ULL : pscan[t - 1];
    if (k >= excl && k < pscan[t]) {
        unsigned long long c = excl;
        #pragma unroll
        for (int i = 0; i < PER; ++i) {
            if (k < c + loc[i]) { res[0] = (unsigned int)(t * PER + i); res[1] = (unsigned int)c; break; }
            c += loc[i];
        }
    }
    __syncthreads();
}

__device__ inline void do_finstats(const unsigned int* scal, const double* g_sum,
                                   float* fscal)
{
    float v0 = key2f(scal[8]), v1 = key2f(scal[9]);
    float mean = __fmul_rn(__fadd_rn(v0, v1), 0.5f);
    double s = g_sum[0], ss = g_sum[1];
    const double NN = (double)NTOT;
    double var = (ss - s * s / NN) / (NN - 1.0);
    if (var < 0.0) var = 0.0;
    float stdf = (float)sqrt(var);
    float rng = __fsub_rn(fscal[4], fscal[3]);
    float coeff = __fdiv_rn(stdf, rng);
    fscal[0] = mean; fscal[1] = stdf; fscal[2] = coeff;
}

// ============ K1: wave-per-token stats + compact + candidate hist (r9 version) ============
__global__ __launch_bounds__(256) void k_token_stats(
    const float4* __restrict__ x4, float* __restrict__ tokmin,
    float* __restrict__ tokmax, float* __restrict__ eulg,
    double* __restrict__ pS, double* __restrict__ pSS,
    float* __restrict__ pMn, float* __restrict__ pMx,
    unsigned int* __restrict__ pcnt, unsigned int* __restrict__ pnlt,
    unsigned int* __restrict__ cbuf, unsigned int* __restrict__ hist1,
    unsigned int* __restrict__ scal)
{
    __shared__ unsigned int lbuf[CSTRIDE];
    __shared__ unsigned int lhist[2048];
    __shared__ unsigned int lcnt;
    __shared__ double wS[4], wSS[4];
    __shared__ float wMn[4], wMx[4];
    __shared__ unsigned int wNlt[4];
    for (int i = threadIdx.x; i < 2048; i += 256) lhist[i] = 0;
    if (threadIdx.x == 0) lcnt = 0;
    __syncthreads();
    const int wave = threadIdx.x >> 6, lane = threadIdx.x & 63;

    double aS0 = 0.0, aS1 = 0.0, aS2 = 0.0, aS3 = 0.0;
    double aQ0 = 0.0, aQ1 = 0.0, aQ2 = 0.0, aQ3 = 0.0;
    float gmn = INFINITY, gmx = -INFINITY;
    unsigned int nlt = 0;

    for (int token = blockIdx.x * 4 + wave; token < NTOK; token += gridDim.x * 4) {
        const float4* xp = x4 + (size_t)token * 192;
        float4 v0 = xp[lane];
        float4 v1 = xp[lane + 64];
        float4 v2 = xp[lane + 128];

        float mnx = fminf(fminf(v0.x, v1.x), v2.x);
        float mny = fminf(fminf(v0.y, v1.y), v2.y);
        float mnz = fminf(fminf(v0.z, v1.z), v2.z);
        float mnw = fminf(fminf(v0.w, v1.w), v2.w);
        float mxx = fmaxf(fmaxf(v0.x, v1.x), v2.x);
        float mxy = fmaxf(fmaxf(v0.y, v1.y), v2.y);
        float mxz = fmaxf(fmaxf(v0.z, v1.z), v2.z);
        float mxw = fmaxf(fmaxf(v0.w, v1.w), v2.w);
        float mn = fminf(fminf(mnx, mny), fminf(mnz, mnw));
        float mx = fmaxf(fmaxf(mxx, mxy), fmaxf(mxz, mxw));

        #pragma unroll
        for (int k = 0; k < 3; ++k) {
            float4 v = (k == 0) ? v0 : (k == 1) ? v1 : v2;
            double dx = (double)v.x, dy = (double)v.y, dz = (double)v.z, dw = (double)v.w;
            aS0 += dx; aS1 += dy; aS2 += dz; aS3 += dw;
            aQ0 = fma(dx, dx, aQ0); aQ1 = fma(dy, dy, aQ1);
            aQ2 = fma(dz, dz, aQ2); aQ3 = fma(dw, dw, aQ3);
            nlt += (v.x < -CTH) + (v.y < -CTH) + (v.z < -CTH) + (v.w < -CTH);
            #pragma unroll
            for (int c = 0; c < 4; ++c) {
                float vv = (c == 0) ? v.x : (c == 1) ? v.y : (c == 2) ? v.z : v.w;
                if (vv < CTH && vv >= -CTH) {
                    unsigned int p = atomicAdd(&lcnt, 1u);
                    if (p < CSTRIDE) {
                        unsigned int key = f2key(vv);
                        lbuf[p] = key;
                        atomicAdd(&lhist[key >> 21], 1u);
                    }
                }
            }
        }
        gmn = fminf(gmn, mn); gmx = fmaxf(gmx, mx);
        #pragma unroll
        for (int d = 1; d < 64; d <<= 1) {
            mn = fminf(mn, __shfl_xor(mn, d));
            mx = fmaxf(mx, __shfl_xor(mx, d));
        }
        if (lane == 0) {
            tokmin[token] = mn; tokmax[token] = mx;
            float e = __fsub_rn(mx, mn);
            if ((token & (TT - 1)) == 0) e = __fmul_rn(e, 1e8f);
            eulg[token] = e;
        }
    }
    double accS = (aS0 + aS1) + (aS2 + aS3);
    double accSS = (aQ0 + aQ1) + (aQ2 + aQ3);
    #pragma unroll
    for (int d = 1; d < 64; d <<= 1) {
        accS  += __shfl_xor(accS, d);
        accSS += __shfl_xor(accSS, d);
        gmn = fminf(gmn, __shfl_xor(gmn, d));
        gmx = fmaxf(gmx, __shfl_xor(gmx, d));
        nlt += __shfl_xor(nlt, d);
    }
    if (lane == 0) { wS[wave] = accS; wSS[wave] = accSS; wMn[wave] = gmn;
                     wMx[wave] = gmx; wNlt[wave] = nlt; }
    __syncthreads();
    if (threadIdx.x == 0) {
        pS[blockIdx.x]  = wS[0] + wS[1] + wS[2] + wS[3];
        pSS[blockIdx.x] = wSS[0] + wSS[1] + wSS[2] + wSS[3];
        pMn[blockIdx.x] = fminf(fminf(wMn[0], wMn[1]), fminf(wMn[2], wMn[3]));
        pMx[blockIdx.x] = fmaxf(fmaxf(wMx[0], wMx[1]), fmaxf(wMx[2], wMx[3]));
        pnlt[blockIdx.x] = wNlt[0] + wNlt[1] + wNlt[2] + wNlt[3];
        unsigned int n = lcnt;
        if (n > CSTRIDE) { scal[10] = 1; n = CSTRIDE; }
        pcnt[blockIdx.x] = n;
        lcnt = n;
    }
    __syncthreads();
    {
        unsigned int n = lcnt;
        for (unsigned int i = threadIdx.x; i < n; i += 256)
            cbuf[blockIdx.x * CSTRIDE + i] = lbuf[i];
        for (int i = threadIdx.x; i < 2048; i += 256) {
            unsigned int c = lhist[i];
            if (c) atomicAdd(&hist1[i], c);
        }
    }
}

// ============ K2: fused 1-block scalars (r10-validated): reduce + sel1 + gather + sel2/3 ============
__global__ __launch_bounds__(1024) void k_scalars(
    const double* __restrict__ pS, const double* __restrict__ pSS,
    const float* __restrict__ pMn, const float* __restrict__ pMx,
    const unsigned int* __restrict__ pnlt, const unsigned int* __restrict__ hist1,
    const unsigned int* __restrict__ pcnt, const unsigned int* __restrict__ cbuf,
    unsigned int* __restrict__ scal, double* __restrict__ g_sum,
    float* __restrict__ fscal)
{
    __shared__ unsigned short spc[2048];
    __shared__ unsigned int hist[2048];
    __shared__ unsigned long long pscan[1024];
    __shared__ unsigned int sres[2];
    __shared__ unsigned int karr[2][KCAP];
    __shared__ unsigned int kcnt[2];
    __shared__ double wredS[16], wredQ[16];
    __shared__ float wredMn[16], wredMx[16];
    __shared__ unsigned int wredN[16];
    __shared__ long long srr[2];
    __shared__ unsigned int sbkt[2], srnk[2];
    __shared__ unsigned int sflag;
    const int t = threadIdx.x, wid = t >> 6, lane = t & 63;

    double a = pS[t] + pS[t + 1024];
    double b = pSS[t] + pSS[t + 1024];
    float  c = fminf(pMn[t], pMn[t + 1024]);
    float  d = fmaxf(pMx[t], pMx[t + 1024]);
    unsigned int f = pnlt[t] + pnlt[t + 1024];
    #pragma unroll
    for (int s = 1; s < 64; s <<= 1) {
        a += __shfl_xor(a, s); b += __shfl_xor(b, s);
        c = fminf(c, __shfl_xor(c, s)); d = fmaxf(d, __shfl_xor(d, s));
        f += __shfl_xor(f, s);
    }
    if (lane == 0) { wredS[wid] = a; wredQ[wid] = b; wredMn[wid] = c;
                     wredMx[wid] = d; wredN[wid] = f; }
    spc[t] = (unsigned short)pcnt[t];
    spc[t + 1024] = (unsigned short)pcnt[t + 1024];
    __syncthreads();
    if (t == 0) {
        double A = 0, B = 0; float C = INFINITY, D = -INFINITY;
        unsigned long long F = 0;
        for (int i = 0; i < 16; ++i) {
            A += wredS[i]; B += wredQ[i];
            C = fminf(C, wredMn[i]); D = fmaxf(D, wredMx[i]);
            F += wredN[i];
        }
        g_sum[0] = A; g_sum[1] = B; fscal[3] = C; fscal[4] = D;
        long long nlt = (long long)F;
        srr[0] = RANK0 - nlt; srr[1] = RANK1 - nlt;
        unsigned int fl = scal[10];
        if (srr[0] < 0 || srr[1] < 0) fl = 1;
        sflag = fl;
        kcnt[0] = 0; kcnt[1] = 0;
    }
    __syncthreads();

    for (int r = 0; r < 2; ++r) {
        unsigned long long rin = (srr[r] < 0) ? 0ULL : (unsigned long long)srr[r];
        sel1024<2048>(hist1, rin, sres, pscan);
        if (t == 0) {
            unsigned long long total = pscan[1023];
            if (srr[r] < 0 || rin >= total) sflag = 1;
            else { sbkt[r] = sres[0]; srnk[r] = (unsigned int)(rin - sres[1]); }
        }
        __syncthreads();
    }
    if (sflag) { if (t == 0) scal[10] = 1; return; }

    const unsigned int b0 = sbkt[0], b1 = sbkt[1];
    for (unsigned int i = t; i < NBLK * CSTRIDE; i += 1024) {
        if ((i & (CSTRIDE - 1)) < spc[i >> 6]) {
            unsigned int k = cbuf[i];
            unsigned int bkt = k >> 21;
            if (bkt == b0) { unsigned int p = atomicAdd(&kcnt[0], 1u); if (p < KCAP) karr[0][p] = k; }
            else if (bkt == b1) { unsigned int p = atomicAdd(&kcnt[1], 1u); if (p < KCAP) karr[1][p] = k; }
        }
    }
    __syncthreads();
    if (t == 0 && (kcnt[0] > KCAP || kcnt[1] > KCAP)) sflag = 1;
    __syncthreads();
    if (sflag) { if (t == 0) scal[10] = 1; return; }

    for (int r = 0; r < 2; ++r) {
        int use = (r == 1 && b1 != b0) ? 1 : 0;
        const unsigned int m = kcnt[use];
        unsigned long long rin = srnk[r];
        for (int i = t; i < 2048; i += 1024) hist[i] = 0;
        __syncthreads();
        for (unsigned int i = t; i < m; i += 1024)
            atomicAdd(&hist[(karr[use][i] >> 10) & 2047u], 1u);
        __syncthreads();
        sel1024<2048>(hist, rin, sres, pscan);
        unsigned int b2 = sres[0]; rin -= sres[1];
        __syncthreads();
        for (int i = t; i < 1024; i += 1024) hist[i] = 0;
        __syncthreads();
        for (unsigned int i = t; i < m; i += 1024) {
            unsigned int k = karr[use][i];
            if (((k >> 10) & 2047u) == b2) atomicAdd(&hist[k & 1023u], 1u);
        }
        __syncthreads();
        sel1024<1024>(hist, rin, sres, pscan);
        if (t == 0) scal[8 + r] = ((r ? b1 : b0) << 21) | (b2 << 10) | sres[0];
        __syncthreads();
    }
    if (t == 0) { scal[10] = 0; do_finstats(scal, g_sum, fscal); }
}

// ============ correctness fallback: exact 3-level select over all x (never taken) ============
__global__ __launch_bounds__(1024) void k_fallback(const float4* __restrict__ x4,
    unsigned int* __restrict__ scal, const double* __restrict__ g_sum,
    float* __restrict__ fscal)
{
    if (!scal[10]) return;
    __shared__ unsigned int h[2][2048];
    __shared__ unsigned long long pscan[1024];
    __shared__ unsigned int sres[2];
    __shared__ unsigned int sb1[2], sb2[2];
    __shared__ unsigned long long srank[2];
    const int t = threadIdx.x;
    const long long n4 = NTOT / 4;
    for (int i = t; i < 2048; i += 1024) h[0][i] = 0;
    __syncthreads();
    for (long long i = t; i < n4; i += 1024) {
        float4 v = x4[i];
        atomicAdd(&h[0][f2key(v.x) >> 21], 1u);
        atomicAdd(&h[0][f2key(v.y) >> 21], 1u);
        atomicAdd(&h[0][f2key(v.z) >> 21], 1u);
        atomicAdd(&h[0][f2key(v.w) >> 21], 1u);
    }
    __syncthreads();
    for (int r = 0; r < 2; ++r) {
        sel1024<2048>(h[0], r ? RANK1 : RANK0, sres, pscan);
        if (t == 0) { sb1[r] = sres[0]; srank[r] = (r ? RANK1 : RANK0) - sres[1]; }
        __syncthreads();
    }
    for (int i = t; i < 4096; i += 1024) ((unsigned int*)h)[i] = 0;
    __syncthreads();
    for (long long i = t; i < n4; i += 1024) {
        float4 v = x4[i];
        #pragma unroll
        for (int cc = 0; cc < 4; ++cc) {
            float fv = (cc == 0) ? v.x : (cc == 1) ? v.y : (cc == 2) ? v.z : v.w;
            unsigned int k = f2key(fv);
            unsigned int top = k >> 21, mid = (k >> 10) & 2047u;
            if (top == sb1[0]) atomicAdd(&h[0][mid], 1u);
            if (top == sb1[1]) atomicAdd(&h[1][mid], 1u);
        }
    }
    __syncthreads();
    for (int r = 0; r < 2; ++r) {
        sel1024<2048>(h[r], srank[r], sres, pscan);
        if (t == 0) { sb2[r] = sres[0]; srank[r] -= sres[1]; }
        __syncthreads();
    }
    for (int i = t; i < 4096; i += 1024) ((unsigned int*)h)[i] = 0;
    __syncthreads();
    for (long long i = t; i < n4; i += 1024) {
        float4 v = x4[i];
        #pragma unroll
        for (int cc = 0; cc < 4; ++cc) {
            float fv = (cc == 0) ? v.x : (cc == 1) ? v.y : (cc == 2) ? v.z : v.w;
            unsigned int k = f2key(fv);
            unsigned int t22 = k >> 10, low = k & 1023u;
            if (t22 == ((sb1[0] << 11) | sb2[0])) atomicAdd(&h[0][low], 1u);
            if (t22 == ((sb1[1] << 11) | sb2[1])) atomicAdd(&h[1][low], 1u);
        }
    }
    __syncthreads();
    for (int r = 0; r < 2; ++r) {
        sel1024<1024>(h[r], srank[r], sres, pscan);
        if (t == 0) scal[8 + r] = (sb1[r] << 21) | (sb2[r] << 10) | sres[0];
        __syncthreads();
    }
    if (t == 0) do_finstats(scal, g_sum, fscal);
}

// ============ K3: wave-per-token band counts -> attn_std ============
__global__ __launch_bounds__(256) void k_count(const float4* __restrict__ x4,
    const float* __restrict__ eulg, const float* __restrict__ fscal, float* __restrict__ attn)
{
    const int wave = threadIdx.x >> 6, lane = threadIdx.x & 63;
    const float mean = fscal[0], coeff = fscal[2];
    for (int token = blockIdx.x * 4 + wave; token < NTOK; token += gridDim.x * 4) {
        float band = __fmul_rn(__fmul_rn(eulg[token], coeff), 0.8f);
        float hi = __fadd_rn(mean, band);
        float lo = __fsub_rn(mean, band);
        const float4* xp = x4 + (size_t)token * 192;
        int d = 0;
        #pragma unroll
        for (int k = 0; k < 3; ++k) {
            float4 v = xp[lane + k * 64];
            d += (v.x < hi) - (v.x < lo) + (v.y < hi) - (v.y < lo)
               + (v.z < hi) - (v.z < lo) + (v.w < hi) - (v.w < lo);
        }
        #pragma unroll
        for (int s = 1; s < 64; s <<= 1) d += __shfl_xor(d, s);
        if (lane == 0) {
            float a = fmaxf((float)d, 76.8f);
            float inv = __fdiv_rn(1.0f, a);
            attn[token] = (inv > 1.0f) ? 0.0f : inv;
        }
    }
}

// ============ K4: per-batch stable sort + score + binary-search desc ranks ============
__device__ inline void bitonic_sort(unsigned long long* keys, int tid, int nthr) {
    for (int k = 2; k <= TT; k <<= 1) {
        for (int j = k >> 1; j > 0; j >>= 1) {
            __syncthreads();
            for (int i = tid; i < TT; i += nthr) {
                int l = i ^ j;
                if (l > i) {
                    unsigned long long a = keys[i], c = keys[l];
                    bool up = ((i & k) == 0);
                    if (up ? (a > c) : (a < c)) { keys[i] = c; keys[l] = a; }
                }
            }
        }
    }
    __syncthreads();
}

__global__ __launch_bounds__(1024) void k_sort(const float* __restrict__ eulg,
    const float* __restrict__ attn, const float* __restrict__ fscal,
    unsigned int* __restrict__ nlev)
{
    int bb = blockIdx.x, tid = threadIdx.x;
    __shared__ unsigned long long keys[TT];
    __shared__ float av[TT];
    __shared__ int firstNeg;
    __shared__ int s_diff;
    const float stdf = fscal[1];
    const float THR = (float)(1.0 + 511.0 / 254.0);

    for (int t = tid; t < TT; t += 1024) {
        float v = eulg[bb * TT + t];
        keys[t] = ((unsigned long long)f2key(v) << 32) | (unsigned int)t;
    }
    if (tid == 0) firstNeg = TT;
    __syncthreads();
    bitonic_sort(keys, tid, 1024);

    for (int t = tid; t < TT; t += 1024)
        av[t] = attn[bb * TT + (unsigned int)(keys[t] & 0xffffffffu)];
    __syncthreads();

    for (int i = tid; i < TT; i += 1024) {
        float vi = key2f((unsigned int)(keys[i] >> 32));
        float vd = key2f((unsigned int)(keys[TT - 1 - i] >> 32));
        float a  = __fmul_rn(vd, av[TT - 1 - i]);
        float bt = __fmul_rn(__fmul_rn(vi, av[i]), THR);
        float sc = __fdiv_rn(__fsub_rn(a, bt), stdf);
        if (sc < 0.0f) atomicMin(&firstNeg, i);
    }
    __syncthreads();
    if (tid == 0) {
        int mi = (firstNeg >= TT) ? 0 : firstNeg;
        s_diff = (mi - 1 > 0) ? (mi - 1) : 0;
    }
    __syncthreads();
    int diffv = s_diff;

    for (int i = tid; i < TT; i += 1024) {
        unsigned long long key = keys[i];
        unsigned int ku = (unsigned int)(key >> 32);
        unsigned long long tlo = ((unsigned long long)ku) << 32;
        int a = 0;
        for (int st = 1024; st > 0; st >>= 1) {
            int c = a + st;
            if (c <= TT && keys[c - 1] < tlo) a = c;
        }
        int b1;
        if (ku == 0xFFFFFFFFu) b1 = TT;
        else {
            unsigned long long thi = ((unsigned long long)(ku + 1)) << 32;
            b1 = 0;
            for (int st = 1024; st > 0; st >>= 1) {
                int c = b1 + st;
                if (c <= TT && keys[c - 1] < thi) b1 = c;
            }
        }
        int rank = TT - b1 + i - a;
        unsigned int token = (unsigned int)(key & 0xffffffffu);
        unsigned int levels = (rank > TT - 2 - diffv) ? 128u
                            : ((rank <= diffv) ? 512u : 256u);
        nlev[bb * TT + token] = levels;
    }
}

// ============ K5: wave-per-token quantize / dequantize (x direct, nt stores) ============
__global__ __launch_bounds__(256) void k_quant(const float4* __restrict__ x4,
    const float* __restrict__ tokmin, const float* __restrict__ tokmax,
    const unsigned int* __restrict__ nlev, float4* __restrict__ out)
{
    const int wave = threadIdx.x >> 6, lane = threadIdx.x & 63;
    for (int token = blockIdx.x * 4 + wave; token < NTOK; token += gridDim.x * 4) {
        float mn = tokmin[token], mx = tokmax[token];
        float delta = fmaxf(__fdiv_rn(__fsub_rn(mx, mn), 255.0f), 1e-8f);
        float zp = rintf(__fdiv_rn(-mn, delta));
        float nlm1 = (float)(nlev[token] - 1u);
        const float4* xp = x4 + (size_t)token * 192;
        nf4* op = (nf4*)(out + (size_t)token * 192);
        #pragma unroll
        for (int k = 0; k < 3; ++k) {
            float4 v = xp[lane + k * 64];
            nf4 r;
            #pragma unroll
            for (int c = 0; c < 4; ++c) {
                float vv = (c == 0) ? v.x : (c == 1) ? v.y : (c == 2) ? v.z : v.w;
                float xi = __fadd_rn(rintf(__fdiv_rn(vv, delta)), zp);
                float t = __fdiv_rn(xi, nlm1);
                t = fminf(fmaxf(t, 0.0f), 1.0f);
                float xq = __fmul_rn(t, nlm1);
                r[c] = __fmul_rn(__fsub_rn(xq, zp), delta);
            }
            __builtin_nontemporal_store(r, &op[lane + k * 64]);
        }
    }
}

extern "C" void kernel_launch(void* const* d_in, const int* in_sizes, int n_in,
                              void* d_out, int out_size, void* d_ws, size_t ws_size,
                              hipStream_t stream)
{
    (void)in_sizes; (void)n_in; (void)out_size; (void)ws_size;
    const float* x = (const float*)d_in[0];
    float* out = (float*)d_out;
    char* ws = (char*)d_ws;

    double* g_sum = (double*)ws;                           // [0]=sum [1]=sumsq
    unsigned int* scal = (unsigned int*)(ws + 16);         // [8..9]=keys [10]=flag
    float* fscal = (float*)(ws + 96);                      // mean,std,coeff,gmin,gmax
    unsigned int* hist1 = (unsigned int*)(ws + 128);       // 2048 -> 8320
    float* tokmin = (float*)(ws + 16384);
    float* tokmax = tokmin + NTOK;
    float* eulg   = tokmax + NTOK;
    float* attn   = eulg + NTOK;
    unsigned int* nlev = (unsigned int*)(attn + NTOK);     // ends 1327104
    double* pS  = (double*)(ws + 1327104);
    double* pSS = pS + 2048;
    float* pMn  = (float*)(pSS + 2048);
    float* pMx  = pMn + 2048;
    unsigned int* pcnt = (unsigned int*)(ws + 1376256);
    unsigned int* pnlt = (unsigned int*)(ws + 1384448);
    unsigned int* cbuf = (unsigned int*)(ws + 1392640);    // 512 KB -> 1916928

    (void)hipMemsetAsync(ws, 0, 8320, stream);             // g_sum + scal + hist1

    k_token_stats<<<NBLK, 256, 0, stream>>>((const float4*)x, tokmin, tokmax, eulg,
                                            pS, pSS, pMn, pMx, pcnt, pnlt, cbuf,
                                            hist1, scal);
    k_scalars<<<1, 1024, 0, stream>>>(pS, pSS, pMn, pMx, pnlt, hist1, pcnt, cbuf,
                                      scal, g_sum, fscal);
    k_fallback<<<1, 1024, 0, stream>>>((const float4*)x, scal, g_sum, fscal);
    k_count<<<NBLK, 256, 0, stream>>>((const float4*)x, eulg, fscal, attn);
    k_sort<<<BB, 1024, 0, stream>>>(eulg, attn, fscal, nlev);
    k_quant<<<NBLK, 256, 0, stream>>>((const float4*)x, tokmin, tokmax, nlev, (float4*)out);
}

// Round 12
// 213.631 us; speedup vs baseline: 1.2014x; 1.2014x over previous
//
#include <hip/hip_runtime.h>
#include <stdint.h>
#include <math.h>

#define BB 32
#define TT 2048
#define CC 768
#define NTOK (BB*TT)                     // 65536
#define NTOT 50331648LL                  // BB*TT*CC
#define RANK0 25165823LL                 // NTOT/2 - 1
#define RANK1 25165824LL                 // NTOT/2
#define CTH 0.0009765625f                // 2^-10
#define NBLK 2048
#define CSTRIDE 64                       // compact slots per block
#define GCAP 4096                        // per-bucket gather capacity

typedef float nf4 __attribute__((ext_vector_type(4)));   // native vec for nontemporal

// ---- monotone float<->uint mapping (order-preserving) ----
__device__ inline unsigned int f2key(float f) {
    unsigned int u = __float_as_uint(f);
    return (u & 0x80000000u) ? ~u : (u | 0x80000000u);
}
__device__ inline float key2f(unsigned int k) {
    unsigned int u = (k & 0x80000000u) ? (k ^ 0x80000000u) : ~k;
    return __uint_as_float(u);
}

// ---- 256-thread bucket select ----
template<int NB>
__device__ void sel256(const unsigned int* __restrict__ hist,
                       unsigned long long k, unsigned int* res)
{
    const int t = threadIdx.x;
    constexpr int PER = NB / 256;
    unsigned int loc[PER];
    unsigned long long lsum = 0;
    #pragma unroll
    for (int i = 0; i < PER; ++i) { loc[i] = hist[t * PER + i]; lsum += loc[i]; }
    __shared__ unsigned long long pscan[256];
    pscan[t] = lsum;
    __syncthreads();
    #pragma unroll
    for (int off = 1; off < 256; off <<= 1) {
        unsigned long long v = (t >= off) ? pscan[t - off] : 0ULL;
        __syncthreads();
        pscan[t] += v;
        __syncthreads();
    }
    unsigned long long excl = (t == 0) ? 0ULL : pscan[t - 1];
    if (k >= excl && k < pscan[t]) {
        unsigned long long c = excl;
        #pragma unroll
        for (int i = 0; i < PER; ++i) {
            if (k < c + loc[i]) { res[0] = (unsigned int)(t * PER + i); res[1] = (unsigned int)c; break; }
            c += loc[i];
        }
    }
    __syncthreads();
}

// ---- 1024-thread bucket select ----
template<int NB>
__device__ void sel1024(const unsigned int* __restrict__ hist,
                        unsigned long long k, unsigned int* res,
                        unsigned long long* pscan)
{
    const int t = threadIdx.x;
    constexpr int PER = NB / 1024;
    unsigned int loc[PER];
    unsigned long long lsum = 0;
    #pragma unroll
    for (int i = 0; i < PER; ++i) { loc[i] = hist[t * PER + i]; lsum += loc[i]; }
    pscan[t] = lsum;
    __syncthreads();
    for (int off = 1; off < 1024; off <<= 1) {
        unsigned long long v = (t >= off) ? pscan[t - off] : 0ULL;
        __syncthreads();
        pscan[t] += v;
        __syncthreads();
    }
    unsigned long long excl = (t == 0) ? 0ULL : pscan[t - 1];
    if (k >= excl && k < pscan[t]) {
        unsigned long long c = excl;
        #pragma unroll
        for (int i = 0; i < PER; ++i) {
            if (k < c + loc[i]) { res[0] = (unsigned int)(t * PER + i); res[1] = (unsigned int)c; break; }
            c += loc[i];
        }
    }
    __syncthreads();
}

__device__ inline void do_finstats(const unsigned int* scal, const double* g_sum,
                                   float* fscal)
{
    float v0 = key2f(scal[8]), v1 = key2f(scal[9]);
    float mean = __fmul_rn(__fadd_rn(v0, v1), 0.5f);
    double s = g_sum[0], ss = g_sum[1];
    const double NN = (double)NTOT;
    double var = (ss - s * s / NN) / (NN - 1.0);
    if (var < 0.0) var = 0.0;
    float stdf = (float)sqrt(var);
    float rng = __fsub_rn(fscal[4], fscal[3]);
    float coeff = __fdiv_rn(stdf, rng);
    fscal[0] = mean; fscal[1] = stdf; fscal[2] = coeff;
}

// ============ K1: wave-per-token stats + candidate compact + candidate hist ============
__global__ __launch_bounds__(256) void k_token_stats(
    const float4* __restrict__ x4, float* __restrict__ tokmin,
    float* __restrict__ tokmax, float* __restrict__ eulg,
    double* __restrict__ pS, double* __restrict__ pSS,
    float* __restrict__ pMn, float* __restrict__ pMx,
    unsigned int* __restrict__ pcnt, unsigned int* __restrict__ pnlt,
    unsigned int* __restrict__ cbuf, unsigned int* __restrict__ hist1,
    unsigned int* __restrict__ scal)
{
    __shared__ unsigned int lbuf[CSTRIDE];
    __shared__ unsigned int lhist[2048];
    __shared__ unsigned int lcnt;
    __shared__ double wS[4], wSS[4];
    __shared__ float wMn[4], wMx[4];
    __shared__ unsigned int wNlt[4];
    for (int i = threadIdx.x; i < 2048; i += 256) lhist[i] = 0;
    if (threadIdx.x == 0) lcnt = 0;
    __syncthreads();
    const int wave = threadIdx.x >> 6, lane = threadIdx.x & 63;

    double aS0 = 0.0, aS1 = 0.0, aS2 = 0.0, aS3 = 0.0;
    double aQ0 = 0.0, aQ1 = 0.0, aQ2 = 0.0, aQ3 = 0.0;
    float gmn = INFINITY, gmx = -INFINITY;
    unsigned int nlt = 0;

    for (int token = blockIdx.x * 4 + wave; token < NTOK; token += gridDim.x * 4) {
        const float4* xp = x4 + (size_t)token * 192;
        float4 v0 = xp[lane];
        float4 v1 = xp[lane + 64];
        float4 v2 = xp[lane + 128];

        float mnx = fminf(fminf(v0.x, v1.x), v2.x);
        float mny = fminf(fminf(v0.y, v1.y), v2.y);
        float mnz = fminf(fminf(v0.z, v1.z), v2.z);
        float mnw = fminf(fminf(v0.w, v1.w), v2.w);
        float mxx = fmaxf(fmaxf(v0.x, v1.x), v2.x);
        float mxy = fmaxf(fmaxf(v0.y, v1.y), v2.y);
        float mxz = fmaxf(fmaxf(v0.z, v1.z), v2.z);
        float mxw = fmaxf(fmaxf(v0.w, v1.w), v2.w);
        float mn = fminf(fminf(mnx, mny), fminf(mnz, mnw));
        float mx = fmaxf(fmaxf(mxx, mxy), fmaxf(mxz, mxw));

        #pragma unroll
        for (int k = 0; k < 3; ++k) {
            float4 v = (k == 0) ? v0 : (k == 1) ? v1 : v2;
            double dx = (double)v.x, dy = (double)v.y, dz = (double)v.z, dw = (double)v.w;
            aS0 += dx; aS1 += dy; aS2 += dz; aS3 += dw;
            aQ0 = fma(dx, dx, aQ0); aQ1 = fma(dy, dy, aQ1);
            aQ2 = fma(dz, dz, aQ2); aQ3 = fma(dw, dw, aQ3);
            nlt += (v.x < -CTH) + (v.y < -CTH) + (v.z < -CTH) + (v.w < -CTH);
            #pragma unroll
            for (int c = 0; c < 4; ++c) {
                float vv = (c == 0) ? v.x : (c == 1) ? v.y : (c == 2) ? v.z : v.w;
                if (vv < CTH && vv >= -CTH) {
                    unsigned int p = atomicAdd(&lcnt, 1u);
                    if (p < CSTRIDE) {
                        unsigned int key = f2key(vv);
                        lbuf[p] = key;
                        atomicAdd(&lhist[key >> 21], 1u);
                    }
                }
            }
        }
        gmn = fminf(gmn, mn); gmx = fmaxf(gmx, mx);
        #pragma unroll
        for (int d = 1; d < 64; d <<= 1) {
            mn = fminf(mn, __shfl_xor(mn, d));
            mx = fmaxf(mx, __shfl_xor(mx, d));
        }
        if (lane == 0) {
            tokmin[token] = mn; tokmax[token] = mx;
            float e = __fsub_rn(mx, mn);
            if ((token & (TT - 1)) == 0) e = __fmul_rn(e, 1e8f);
            eulg[token] = e;
        }
    }
    double accS = (aS0 + aS1) + (aS2 + aS3);
    double accSS = (aQ0 + aQ1) + (aQ2 + aQ3);
    #pragma unroll
    for (int d = 1; d < 64; d <<= 1) {
        accS  += __shfl_xor(accS, d);
        accSS += __shfl_xor(accSS, d);
        gmn = fminf(gmn, __shfl_xor(gmn, d));
        gmx = fmaxf(gmx, __shfl_xor(gmx, d));
        nlt += __shfl_xor(nlt, d);
    }
    if (lane == 0) { wS[wave] = accS; wSS[wave] = accSS; wMn[wave] = gmn;
                     wMx[wave] = gmx; wNlt[wave] = nlt; }
    __syncthreads();
    if (threadIdx.x == 0) {
        pS[blockIdx.x]  = wS[0] + wS[1] + wS[2] + wS[3];
        pSS[blockIdx.x] = wSS[0] + wSS[1] + wSS[2] + wSS[3];
        pMn[blockIdx.x] = fminf(fminf(wMn[0], wMn[1]), fminf(wMn[2], wMn[3]));
        pMx[blockIdx.x] = fmaxf(fmaxf(wMx[0], wMx[1]), fmaxf(wMx[2], wMx[3]));
        pnlt[blockIdx.x] = wNlt[0] + wNlt[1] + wNlt[2] + wNlt[3];
        unsigned int n = lcnt;
        if (n > CSTRIDE) { scal[10] = 1; n = CSTRIDE; }
        pcnt[blockIdx.x] = n;
        lcnt = n;
    }
    __syncthreads();
    {
        unsigned int n = lcnt;
        for (unsigned int i = threadIdx.x; i < n; i += 256)
            cbuf[blockIdx.x * CSTRIDE + i] = lbuf[i];
        for (int i = threadIdx.x; i < 2048; i += 256) {
            unsigned int c = lhist[i];
            if (c) atomicAdd(&hist1[i], c);
        }
    }
}

// ============ K2a: 1-block reduce + level-1 select on global candidate hist ============
__global__ __launch_bounds__(1024) void k_scalars_a(
    const double* __restrict__ pS, const double* __restrict__ pSS,
    const float* __restrict__ pMn, const float* __restrict__ pMx,
    const unsigned int* __restrict__ pnlt, const unsigned int* __restrict__ hist1,
    unsigned int* __restrict__ scal, double* __restrict__ g_sum,
    float* __restrict__ fscal)
{
    __shared__ double a[1024], b[1024];
    __shared__ float c[1024], d[1024];
    __shared__ unsigned int f[1024];
    __shared__ unsigned long long pscan[1024];
    __shared__ unsigned int sres[2];
    __shared__ long long srr[2];
    __shared__ unsigned int sflag;
    const int t = threadIdx.x;

    a[t] = pS[t] + pS[t + 1024];
    b[t] = pSS[t] + pSS[t + 1024];
    c[t] = fminf(pMn[t], pMn[t + 1024]);
    d[t] = fmaxf(pMx[t], pMx[t + 1024]);
    f[t] = pnlt[t] + pnlt[t + 1024];
    __syncthreads();
    for (int st = 512; st > 0; st >>= 1) {
        if (t < st) {
            a[t] += a[t + st]; b[t] += b[t + st];
            c[t] = fminf(c[t], c[t + st]); d[t] = fmaxf(d[t], d[t + st]);
            f[t] += f[t + st];
        }
        __syncthreads();
    }
    if (t == 0) {
        g_sum[0] = a[0]; g_sum[1] = b[0]; fscal[3] = c[0]; fscal[4] = d[0];
        long long nlt = (long long)f[0];
        srr[0] = RANK0 - nlt; srr[1] = RANK1 - nlt;
        sflag = scal[10];
        if (srr[0] < 0 || srr[1] < 0) sflag = 1;
    }
    __syncthreads();

    for (int r = 0; r < 2; ++r) {
        unsigned long long rin = (srr[r] < 0) ? ~0ULL : (unsigned long long)srr[r];
        sel1024<2048>(hist1, rin, sres, pscan);
        unsigned long long total = pscan[1023];
        if (t == 0) {
            if (rin >= total) sflag = 1;
            else { scal[2 + r] = sres[0]; scal[4 + r] = (unsigned int)(rin - sres[1]); }
        }
        __syncthreads();
    }
    if (t == 0) scal[10] = sflag;
}

// ============ K2b: grid gather of candidates in selected buckets ============
__global__ __launch_bounds__(256) void k_gather(
    const unsigned int* __restrict__ cbuf, const unsigned int* __restrict__ pcnt,
    const unsigned int* __restrict__ scal, unsigned int* __restrict__ gcnt,
    unsigned int* __restrict__ gbuf0, unsigned int* __restrict__ gbuf1)
{
    if (scal[10]) return;
    const unsigned int b0 = scal[2], b1 = scal[3];
    const unsigned int nslots = NBLK * CSTRIDE;
    for (unsigned int i = blockIdx.x * 256 + threadIdx.x; i < nslots;
         i += gridDim.x * 256) {
        if ((i & (CSTRIDE - 1)) < pcnt[i >> 6]) {
            unsigned int k = cbuf[i];
            unsigned int bkt = k >> 21;
            if (bkt == b0) {
                unsigned int p = atomicAdd(&gcnt[0], 1u);
                if (p < GCAP) gbuf0[p] = k;
            }
            if (bkt == b1 && b1 != b0) {
                unsigned int p = atomicAdd(&gcnt[1], 1u);
                if (p < GCAP) gbuf1[p] = k;
            }
        }
    }
}

// ============ K2c: 1-block exact select over gathered keys ============
__global__ __launch_bounds__(256) void k_median_final(
    unsigned int* __restrict__ scal, const unsigned int* __restrict__ gcnt,
    const unsigned int* __restrict__ gbuf0, const unsigned int* __restrict__ gbuf1,
    const double* __restrict__ g_sum, float* __restrict__ fscal)
{
    __shared__ unsigned int karr[GCAP];
    __shared__ unsigned int hist[2048];
    __shared__ unsigned int sres[2];
    __shared__ unsigned int sflag;
    const int t = threadIdx.x;
    if (t == 0) {
        unsigned int fl = scal[10];
        if (gcnt[0] > GCAP || gcnt[1] > GCAP) fl = 1;
        scal[10] = fl; sflag = fl;
    }
    __syncthreads();
    if (sflag) return;

    const unsigned int b0 = scal[2], b1 = scal[3];
    for (int r = 0; r < 2; ++r) {
        const bool use0 = (r == 0) || (b1 == b0);
        const unsigned int* gb = use0 ? gbuf0 : gbuf1;
        const unsigned int m = use0 ? gcnt[0] : gcnt[1];
        unsigned long long rin = scal[4 + r];
        for (unsigned int i = t; i < m; i += 256) karr[i] = gb[i];
        for (int i = t; i < 2048; i += 256) hist[i] = 0;
        __syncthreads();
        for (unsigned int i = t; i < m; i += 256)
            atomicAdd(&hist[(karr[i] >> 10) & 2047u], 1u);
        __syncthreads();
        sel256<2048>(hist, rin, sres);
        unsigned int b2 = sres[0]; rin -= sres[1];
        __syncthreads();
        for (int i = t; i < 1024; i += 256) hist[i] = 0;
        __syncthreads();
        for (unsigned int i = t; i < m; i += 256) {
            unsigned int k = karr[i];
            if (((k >> 10) & 2047u) == b2) atomicAdd(&hist[k & 1023u], 1u);
        }
        __syncthreads();
        sel256<1024>(hist, rin, sres);
        if (t == 0) {
            unsigned int bkt = r ? b1 : b0;
            scal[8 + r] = (bkt << 21) | (b2 << 10) | sres[0];
        }
        __syncthreads();
    }
    if (t == 0) do_finstats(scal, g_sum, fscal);
}

// ============ correctness fallback: exact 3-level select over all x (never taken) ============
__global__ __launch_bounds__(1024) void k_fallback(const float4* __restrict__ x4,
    unsigned int* __restrict__ scal, const double* __restrict__ g_sum,
    float* __restrict__ fscal)
{
    if (!scal[10]) return;
    __shared__ unsigned int h[2][2048];
    __shared__ unsigned long long pscan[1024];
    __shared__ unsigned int sres[2];
    __shared__ unsigned int sb1[2], sb2[2];
    __shared__ unsigned long long srank[2];
    const int t = threadIdx.x;
    const long long n4 = NTOT / 4;
    for (int i = t; i < 2048; i += 1024) h[0][i] = 0;
    __syncthreads();
    for (long long i = t; i < n4; i += 1024) {
        float4 v = x4[i];
        atomicAdd(&h[0][f2key(v.x) >> 21], 1u);
        atomicAdd(&h[0][f2key(v.y) >> 21], 1u);
        atomicAdd(&h[0][f2key(v.z) >> 21], 1u);
        atomicAdd(&h[0][f2key(v.w) >> 21], 1u);
    }
    __syncthreads();
    for (int r = 0; r < 2; ++r) {
        sel1024<2048>(h[0], r ? RANK1 : RANK0, sres, pscan);
        if (t == 0) { sb1[r] = sres[0]; srank[r] = (r ? RANK1 : RANK0) - sres[1]; }
        __syncthreads();
    }
    for (int i = t; i < 4096; i += 1024) ((unsigned int*)h)[i] = 0;
    __syncthreads();
    for (long long i = t; i < n4; i += 1024) {
        float4 v = x4[i];
        #pragma unroll
        for (int cc = 0; cc < 4; ++cc) {
            float fv = (cc == 0) ? v.x : (cc == 1) ? v.y : (cc == 2) ? v.z : v.w;
            unsigned int k = f2key(fv);
            unsigned int top = k >> 21, mid = (k >> 10) & 2047u;
            if (top == sb1[0]) atomicAdd(&h[0][mid], 1u);
            if (top == sb1[1]) atomicAdd(&h[1][mid], 1u);
        }
    }
    __syncthreads();
    for (int r = 0; r < 2; ++r) {
        sel1024<2048>(h[r], srank[r], sres, pscan);
        if (t == 0) { sb2[r] = sres[0]; srank[r] -= sres[1]; }
        __syncthreads();
    }
    for (int i = t; i < 4096; i += 1024) ((unsigned int*)h)[i] = 0;
    __syncthreads();
    for (long long i = t; i < n4; i += 1024) {
        float4 v = x4[i];
        #pragma unroll
        for (int cc = 0; cc < 4; ++cc) {
            float fv = (cc == 0) ? v.x : (cc == 1) ? v.y : (cc == 2) ? v.z : v.w;
            unsigned int k = f2key(fv);
            unsigned int t22 = k >> 10, low = k & 1023u;
            if (t22 == ((sb1[0] << 11) | sb2[0])) atomicAdd(&h[0][low], 1u);
            if (t22 == ((sb1[1] << 11) | sb2[1])) atomicAdd(&h[1][low], 1u);
        }
    }
    __syncthreads();
    for (int r = 0; r < 2; ++r) {
        sel1024<1024>(h[r], srank[r], sres, pscan);
        if (t == 0) scal[8 + r] = (sb1[r] << 21) | (sb2[r] << 10) | sres[0];
        __syncthreads();
    }
    if (t == 0) do_finstats(scal, g_sum, fscal);
}

// ============ K3: wave-per-token band counts -> attn_std ============
__global__ __launch_bounds__(256) void k_count(const float4* __restrict__ x4,
    const float* __restrict__ eulg, const float* __restrict__ fscal, float* __restrict__ attn)
{
    const int wave = threadIdx.x >> 6, lane = threadIdx.x & 63;
    const float mean = fscal[0], coeff = fscal[2];
    for (int token = blockIdx.x * 4 + wave; token < NTOK; token += gridDim.x * 4) {
        float band = __fmul_rn(__fmul_rn(eulg[token], coeff), 0.8f);
        float hi = __fadd_rn(mean, band);
        float lo = __fsub_rn(mean, band);
        const float4* xp = x4 + (size_t)token * 192;
        int d = 0;
        #pragma unroll
        for (int k = 0; k < 3; ++k) {
            float4 v = xp[lane + k * 64];
            d += (v.x < hi) - (v.x < lo) + (v.y < hi) - (v.y < lo)
               + (v.z < hi) - (v.z < lo) + (v.w < hi) - (v.w < lo);
        }
        #pragma unroll
        for (int s = 1; s < 64; s <<= 1) d += __shfl_xor(d, s);
        if (lane == 0) {
            float a = fmaxf((float)d, 76.8f);
            float inv = __fdiv_rn(1.0f, a);
            attn[token] = (inv > 1.0f) ? 0.0f : inv;
        }
    }
}

// ============ K4: per-batch stable sort + score + binary-search desc ranks ============
__device__ inline void bitonic_sort(unsigned long long* keys, int tid, int nthr) {
    for (int k = 2; k <= TT; k <<= 1) {
        for (int j = k >> 1; j > 0; j >>= 1) {
            __syncthreads();
            for (int i = tid; i < TT; i += nthr) {
                int l = i ^ j;
                if (l > i) {
                    unsigned long long a = keys[i], c = keys[l];
                    bool up = ((i & k) == 0);
                    if (up ? (a > c) : (a < c)) { keys[i] = c; keys[l] = a; }
                }
            }
        }
    }
    __syncthreads();
}

__global__ __launch_bounds__(1024) void k_sort(const float* __restrict__ eulg,
    const float* __restrict__ attn, const float* __restrict__ fscal,
    unsigned int* __restrict__ nlev)
{
    int bb = blockIdx.x, tid = threadIdx.x;
    __shared__ unsigned long long keys[TT];
    __shared__ float av[TT];
    __shared__ int firstNeg;
    __shared__ int s_diff;
    const float stdf = fscal[1];
    const float THR = (float)(1.0 + 511.0 / 254.0);

    for (int t = tid; t < TT; t += 1024) {
        float v = eulg[bb * TT + t];
        keys[t] = ((unsigned long long)f2key(v) << 32) | (unsigned int)t;
    }
    if (tid == 0) firstNeg = TT;
    __syncthreads();
    bitonic_sort(keys, tid, 1024);

    for (int t = tid; t < TT; t += 1024)
        av[t] = attn[bb * TT + (unsigned int)(keys[t] & 0xffffffffu)];
    __syncthreads();

    for (int i = tid; i < TT; i += 1024) {
        float vi = key2f((unsigned int)(keys[i] >> 32));
        float vd = key2f((unsigned int)(keys[TT - 1 - i] >> 32));
        float a  = __fmul_rn(vd, av[TT - 1 - i]);
        float bt = __fmul_rn(__fmul_rn(vi, av[i]), THR);
        float sc = __fdiv_rn(__fsub_rn(a, bt), stdf);
        if (sc < 0.0f) atomicMin(&firstNeg, i);
    }
    __syncthreads();
    if (tid == 0) {
        int mi = (firstNeg >= TT) ? 0 : firstNeg;
        s_diff = (mi - 1 > 0) ? (mi - 1) : 0;
    }
    __syncthreads();
    int diffv = s_diff;

    for (int i = tid; i < TT; i += 1024) {
        unsigned long long key = keys[i];
        unsigned int ku = (unsigned int)(key >> 32);
        unsigned long long tlo = ((unsigned long long)ku) << 32;
        int a = 0;
        for (int st = 1024; st > 0; st >>= 1) {
            int c = a + st;
            if (c <= TT && keys[c - 1] < tlo) a = c;
        }
        int b1;
        if (ku == 0xFFFFFFFFu) b1 = TT;
        else {
            unsigned long long thi = ((unsigned long long)(ku + 1)) << 32;
            b1 = 0;
            for (int st = 1024; st > 0; st >>= 1) {
                int c = b1 + st;
                if (c <= TT && keys[c - 1] < thi) b1 = c;
            }
        }
        int rank = TT - b1 + i - a;
        unsigned int token = (unsigned int)(key & 0xffffffffu);
        unsigned int levels = (rank > TT - 2 - diffv) ? 128u
                            : ((rank <= diffv) ? 512u : 256u);
        nlev[bb * TT + token] = levels;
    }
}

// ============ K5: wave-per-token quantize / dequantize (nt stores) ============
__global__ __launch_bounds__(256) void k_quant(const float4* __restrict__ x4,
    const float* __restrict__ tokmin, const float* __restrict__ tokmax,
    const unsigned int* __restrict__ nlev, float4* __restrict__ out)
{
    const int wave = threadIdx.x >> 6, lane = threadIdx.x & 63;
    for (int token = blockIdx.x * 4 + wave; token < NTOK; token += gridDim.x * 4) {
        float mn = tokmin[token], mx = tokmax[token];
        float delta = fmaxf(__fdiv_rn(__fsub_rn(mx, mn), 255.0f), 1e-8f);
        float zp = rintf(__fdiv_rn(-mn, delta));
        float nlm1 = (float)(nlev[token] - 1u);
        const float4* xp = x4 + (size_t)token * 192;
        nf4* op = (nf4*)(out + (size_t)token * 192);
        #pragma unroll
        for (int k = 0; k < 3; ++k) {
            float4 v = xp[lane + k * 64];
            nf4 r;
            #pragma unroll
            for (int c = 0; c < 4; ++c) {
                float vv = (c == 0) ? v.x : (c == 1) ? v.y : (c == 2) ? v.z : v.w;
                float xi = __fadd_rn(rintf(__fdiv_rn(vv, delta)), zp);
                float t = __fdiv_rn(xi, nlm1);
                t = fminf(fmaxf(t, 0.0f), 1.0f);
                float xq = __fmul_rn(t, nlm1);
                r[c] = __fmul_rn(__fsub_rn(xq, zp), delta);
            }
            __builtin_nontemporal_store(r, &op[lane + k * 64]);
        }
    }
}

extern "C" void kernel_launch(void* const* d_in, const int* in_sizes, int n_in,
                              void* d_out, int out_size, void* d_ws, size_t ws_size,
                              hipStream_t stream)
{
    (void)in_sizes; (void)n_in; (void)out_size; (void)ws_size;
    const float* x = (const float*)d_in[0];
    float* out = (float*)d_out;
    char* ws = (char*)d_ws;

    double* g_sum = (double*)ws;                           // [0]=sum [1]=sumsq
    unsigned int* scal = (unsigned int*)(ws + 16);         // [2..5]=sel [8..9]=keys [10]=flag
    unsigned int* gcnt = (unsigned int*)(ws + 64);         // 2 gather counters
    float* fscal = (float*)(ws + 96);                      // mean,std,coeff,gmin,gmax
    unsigned int* hist1 = (unsigned int*)(ws + 128);       // 2048 -> ends 8320
    float* tokmin = (float*)(ws + 16384);
    float* tokmax = tokmin + NTOK;
    float* eulg   = tokmax + NTOK;
    float* attn   = eulg + NTOK;
    unsigned int* nlev = (unsigned int*)(attn + NTOK);     // ends 1327104
    double* pS  = (double*)(ws + 1327104);
    double* pSS = pS + 2048;
    float* pMn  = (float*)(pSS + 2048);
    float* pMx  = pMn + 2048;
    unsigned int* pcnt = (unsigned int*)(ws + 1376256);
    unsigned int* pnlt = (unsigned int*)(ws + 1384448);
    unsigned int* cbuf = (unsigned int*)(ws + 1392640);
    unsigned int* gbuf0 = (unsigned int*)(ws + 1916928);
    unsigned int* gbuf1 = (unsigned int*)(ws + 1933312);

    (void)hipMemsetAsync(ws, 0, 8320, stream);

    k_token_stats<<<NBLK, 256, 0, stream>>>((const float4*)x, tokmin, tokmax, eulg,
                                            pS, pSS, pMn, pMx, pcnt, pnlt, cbuf,
                                            hist1, scal);
    k_scalars_a<<<1, 1024, 0, stream>>>(pS, pSS, pMn, pMx, pnlt, hist1,
                                        scal, g_sum, fscal);
    k_gather<<<128, 256, 0, stream>>>(cbuf, pcnt, scal, gcnt, gbuf0, gbuf1);
    k_median_final<<<1, 256, 0, stream>>>(scal, gcnt, gbuf0, gbuf1, g_sum, fscal);
    k_fallback<<<1, 1024, 0, stream>>>((const float4*)x, scal, g_sum, fscal);
    k_count<<<NBLK, 256, 0, stream>>>((const float4*)x, eulg, fscal, attn);
    k_sort<<<BB, 1024, 0, stream>>>(eulg, attn, fscal, nlev);
    k_quant<<<NBLK, 256, 0, stream>>>((const float4*)x, tokmin, tokmax, nlev, (float4*)out);
}